// Round 6
// baseline (125.428 us; speedup 1.0000x reference)
//
#include <hip/hip_runtime.h>
#include <math.h>

#define BB 16
#define AA 262144
#define GG 128
#define TPB 256
#define NBLK (AA / TPB)   // 1024 blocks, 1 anchor per thread, all 16 images per block

// ws layout (floats), [blk][img] for coalesced main-kernel stores:
//   [0 .. NBLK*BB)             per-block per-image l1 sums   (sum[blk*BB + b])
//   [NBLK*BB .. 2*NBLK*BB)     per-block per-image fg counts

__global__ __launch_bounds__(TPB, 4) void loss_main_kernel(
    const float4* __restrict__ reg,    // [B*A]
    const float4* __restrict__ anc,    // [A]
    const float4* __restrict__ gt,     // [B*G]
    const int*   __restrict__ mi,      // [B*A]
    float* __restrict__ ws_sum,        // [NBLK*BB]
    float* __restrict__ ws_cnt)        // [NBLK*BB]
{
    __shared__ float4 gts[BB * GG];    // 32 KB: (cx, cy, log w, log h)
    __shared__ float redS[BB * 4];
    __shared__ float redC[BB * 4];

    const int t  = threadIdx.x;
    const int bx = blockIdx.x;
    const int a  = bx * TPB + t;

    // deep prefetch: ALL per-anchor global loads issued before any consumption
    int mjv[BB];
#pragma unroll
    for (int b = 0; b < BB; ++b) mjv[b] = mi[b * AA + a];

    float4 r[BB];
#pragma unroll
    for (int b = 0; b < BB; ++b) r[b] = reg[b * AA + a];

    const float4 an = anc[a];

    // stage ALL images' gt boxes, pre-transformed (overlaps with loads above)
#pragma unroll
    for (int i = 0; i < (BB * GG) / TPB; ++i) {
        const float4 g = gt[i * TPB + t];
        const float w = g.z - g.x;
        const float h = g.w - g.y;
        gts[i * TPB + t] = make_float4(g.x + 0.5f * w, g.y + 0.5f * h,
                                       __logf(w), __logf(h));
    }

    // per-anchor invariants
    const float ex_w  = an.z - an.x;
    const float ex_h  = an.w - an.y;
    const float ex_cx = an.x + 0.5f * ex_w;
    const float ex_cy = an.y + 0.5f * ex_h;
    const float inv_w = 1.0f / ex_w;
    const float inv_h = 1.0f / ex_h;
    const float lw    = __logf(ex_w);
    const float lh    = __logf(ex_h);

    __syncthreads();   // gts ready

    const int wv   = t >> 6;
    const int lane = t & 63;

#pragma unroll
    for (int b = 0; b < BB; ++b) {
        const int mj = mjv[b];
        const float4 g = gts[b * GG + (mj < 0 ? 0 : mj)];

        const float dx = (g.x - ex_cx) * inv_w;
        const float dy = (g.y - ex_cy) * inv_h;
        const float dw = g.z - lw;
        const float dh = g.w - lh;

        const float l1 = fabsf(r[b].x - dx) + fabsf(r[b].y - dy) +
                         fabsf(r[b].z - dw) + fabsf(r[b].w - dh);
        float s = (mj >= 0) ? l1 : 0.0f;

        const unsigned long long bal = __ballot(mj >= 0);
#pragma unroll
        for (int o = 32; o > 0; o >>= 1) s += __shfl_down(s, o);

        if (lane == 0) {
            redS[b * 4 + wv] = s;
            redC[b * 4 + wv] = (float)__popcll(bal);
        }
    }
    __syncthreads();

    if (t < BB) {
        const float s = redS[t * 4] + redS[t * 4 + 1] +
                        redS[t * 4 + 2] + redS[t * 4 + 3];
        const float c = redC[t * 4] + redC[t * 4 + 1] +
                        redC[t * 4 + 2] + redC[t * 4 + 3];
        // coalesced 64B bursts: [blk][img]
        ws_sum[bx * BB + t] = s;
        ws_cnt[bx * BB + t] = c;
    }
}

// single block: each wave reduces 4 images (strided over [blk][img] layout)
__global__ __launch_bounds__(TPB) void reduce_final_kernel(
    const float* __restrict__ ws_sum,
    const float* __restrict__ ws_cnt,
    float* __restrict__ out)
{
    __shared__ float per_img[BB];
    const int t    = threadIdx.x;
    const int wv   = t >> 6;
    const int lane = t & 63;

#pragma unroll
    for (int k = 0; k < 4; ++k) {
        const int b = wv * 4 + k;
        float s = 0.0f, c = 0.0f;
#pragma unroll
        for (int i = 0; i < NBLK / 64; ++i) {
            s += ws_sum[(i * 64 + lane) * BB + b];
            c += ws_cnt[(i * 64 + lane) * BB + b];
        }
#pragma unroll
        for (int o = 32; o > 0; o >>= 1) {
            s += __shfl_down(s, o);
            c += __shfl_down(c, o);
        }
        if (lane == 0) per_img[b] = s / fmaxf(1.0f, c);
    }
    __syncthreads();

    if (t == 0) {
        float acc = 0.0f;
#pragma unroll
        for (int b = 0; b < BB; ++b) acc += per_img[b];
        out[0] = acc / (float)BB;
    }
}

extern "C" void kernel_launch(void* const* d_in, const int* in_sizes, int n_in,
                              void* d_out, int out_size, void* d_ws, size_t ws_size,
                              hipStream_t stream) {
    const float4* reg = (const float4*)d_in[0];   // bbox_regression [B,A,4]
    const float4* anc = (const float4*)d_in[1];   // anchors [A,4]
    const float4* gt  = (const float4*)d_in[2];   // gt_boxes [B,G,4]
    const int*    mi  = (const int*)d_in[3];      // matched_idxs [B,A]

    float* ws_sum = (float*)d_ws;
    float* ws_cnt = ws_sum + NBLK * BB;

    loss_main_kernel<<<NBLK, TPB, 0, stream>>>(reg, anc, gt, mi, ws_sum, ws_cnt);
    reduce_final_kernel<<<1, TPB, 0, stream>>>(ws_sum, ws_cnt, (float*)d_out);
}

// Round 7
// 123.411 us; speedup vs baseline: 1.0163x; 1.0163x over previous
//
#include <hip/hip_runtime.h>
#include <math.h>

#define BB 16
#define AA 262144
#define GG 128
#define TPB 256
#define NBLK (AA / TPB)   // 1024 blocks, 1 anchor per thread, all 16 images per block

// ws layout (floats), [blk][img] for coalesced main-kernel stores:
//   [0 .. NBLK*BB)             per-block per-image l1 sums   (sum[blk*BB + b])
//   [NBLK*BB .. 2*NBLK*BB)     per-block per-image fg counts

__global__ __launch_bounds__(TPB, 4) void loss_main_kernel(
    const float4* __restrict__ reg,    // [B*A]
    const float4* __restrict__ anc,    // [A]
    const float4* __restrict__ gt,     // [B*G]
    const int*   __restrict__ mi,      // [B*A]
    float* __restrict__ ws_sum,        // [NBLK*BB]
    float* __restrict__ ws_cnt)        // [NBLK*BB]
{
    __shared__ float4 gts[BB * GG];    // 32 KB: (cx, cy, log w, log h)
    __shared__ float redS[BB * 4];
    __shared__ float redC[BB * 4];

    const int t  = threadIdx.x;
    const int bx = blockIdx.x;
    const int a  = bx * TPB + t;

    // stage ALL images' gt boxes FIRST (loads issued before anything else),
    // pre-transformed to (cx, cy, log w, log h)
#pragma unroll
    for (int i = 0; i < (BB * GG) / TPB; ++i) {
        const float4 g = gt[i * TPB + t];
        const float w = g.z - g.x;
        const float h = g.w - g.y;
        gts[i * TPB + t] = make_float4(g.x + 0.5f * w, g.y + 0.5f * h,
                                       __logf(w), __logf(h));
    }

    // per-anchor invariants (independent of LDS -> overlaps staging)
    const float4 an = anc[a];
    const float ex_w  = an.z - an.x;
    const float ex_h  = an.w - an.y;
    const float ex_cx = an.x + 0.5f * ex_w;
    const float ex_cy = an.y + 0.5f * ex_h;
    const float inv_w = 1.0f / ex_w;
    const float inv_h = 1.0f / ex_h;
    const float lw    = __logf(ex_w);
    const float lh    = __logf(ex_h);

    // prefetch all matched indices + FIRST half of reg (latency hides under barrier)
    int mjv[BB];
#pragma unroll
    for (int b = 0; b < BB; ++b) mjv[b] = mi[b * AA + a];

    float4 r0[8];
#pragma unroll
    for (int j = 0; j < 8; ++j) r0[j] = reg[j * AA + a];

    __syncthreads();   // gts ready

    const int wv   = t >> 6;
    const int lane = t & 63;

#pragma unroll
    for (int half = 0; half < 2; ++half) {
        float4 r[8];
        if (half == 0) {
#pragma unroll
            for (int j = 0; j < 8; ++j) r[j] = r0[j];
        } else {
#pragma unroll
            for (int j = 0; j < 8; ++j) r[j] = reg[(8 + j) * AA + a];
        }

#pragma unroll
        for (int j = 0; j < 8; ++j) {
            const int b  = half * 8 + j;
            const int mj = mjv[b];
            const float4 g = gts[b * GG + (mj < 0 ? 0 : mj)];

            const float dx = (g.x - ex_cx) * inv_w;
            const float dy = (g.y - ex_cy) * inv_h;
            const float dw = g.z - lw;
            const float dh = g.w - lh;

            const float l1 = fabsf(r[j].x - dx) + fabsf(r[j].y - dy) +
                             fabsf(r[j].z - dw) + fabsf(r[j].w - dh);
            float s = (mj >= 0) ? l1 : 0.0f;

            const unsigned long long bal = __ballot(mj >= 0);
#pragma unroll
            for (int o = 32; o > 0; o >>= 1) s += __shfl_down(s, o);

            if (lane == 0) {
                redS[b * 4 + wv] = s;
                redC[b * 4 + wv] = (float)__popcll(bal);
            }
        }
    }
    __syncthreads();

    if (t < BB) {
        const float s = redS[t * 4] + redS[t * 4 + 1] +
                        redS[t * 4 + 2] + redS[t * 4 + 3];
        const float c = redC[t * 4] + redC[t * 4 + 1] +
                        redC[t * 4 + 2] + redC[t * 4 + 3];
        // coalesced 64B bursts: [blk][img]
        ws_sum[bx * BB + t] = s;
        ws_cnt[bx * BB + t] = c;
    }
}

// single block: each wave reduces 4 images (strided over [blk][img] layout)
__global__ __launch_bounds__(TPB) void reduce_final_kernel(
    const float* __restrict__ ws_sum,
    const float* __restrict__ ws_cnt,
    float* __restrict__ out)
{
    __shared__ float per_img[BB];
    const int t    = threadIdx.x;
    const int wv   = t >> 6;
    const int lane = t & 63;

#pragma unroll
    for (int k = 0; k < 4; ++k) {
        const int b = wv * 4 + k;
        float s = 0.0f, c = 0.0f;
#pragma unroll
        for (int i = 0; i < NBLK / 64; ++i) {
            s += ws_sum[(i * 64 + lane) * BB + b];
            c += ws_cnt[(i * 64 + lane) * BB + b];
        }
#pragma unroll
        for (int o = 32; o > 0; o >>= 1) {
            s += __shfl_down(s, o);
            c += __shfl_down(c, o);
        }
        if (lane == 0) per_img[b] = s / fmaxf(1.0f, c);
    }
    __syncthreads();

    if (t == 0) {
        float acc = 0.0f;
#pragma unroll
        for (int b = 0; b < BB; ++b) acc += per_img[b];
        out[0] = acc / (float)BB;
    }
}

extern "C" void kernel_launch(void* const* d_in, const int* in_sizes, int n_in,
                              void* d_out, int out_size, void* d_ws, size_t ws_size,
                              hipStream_t stream) {
    const float4* reg = (const float4*)d_in[0];   // bbox_regression [B,A,4]
    const float4* anc = (const float4*)d_in[1];   // anchors [A,4]
    const float4* gt  = (const float4*)d_in[2];   // gt_boxes [B,G,4]
    const int*    mi  = (const int*)d_in[3];      // matched_idxs [B,A]

    float* ws_sum = (float*)d_ws;
    float* ws_cnt = ws_sum + NBLK * BB;

    loss_main_kernel<<<NBLK, TPB, 0, stream>>>(reg, anc, gt, mi, ws_sum, ws_cnt);
    reduce_final_kernel<<<1, TPB, 0, stream>>>(ws_sum, ws_cnt, (float*)d_out);
}

// Round 8
// 111.585 us; speedup vs baseline: 1.1241x; 1.1060x over previous
//
#include <hip/hip_runtime.h>
#include <math.h>

#define BB 16
#define AA 262144
#define GG 128
#define TPB 256
#define NBLK (AA / TPB)   // 1024 blocks, 1 anchor per thread

// ws layout (floats), [img][blk]:
//   [0 .. BB*NBLK)           per-image per-block l1 sums   (sum[b*NBLK + blk])
//   [BB*NBLK .. 2*BB*NBLK)   per-image per-block fg counts

__global__ __launch_bounds__(TPB, 4) void loss_main_kernel(
    const float4* __restrict__ reg,    // [B*A]
    const float4* __restrict__ anc,    // [A]
    const float4* __restrict__ gt,     // [B*G]
    const int*   __restrict__ mi,      // [B*A]
    float* __restrict__ ws_sum,        // [BB*NBLK]
    float* __restrict__ ws_cnt)        // [BB*NBLK]
{
    __shared__ float4 gts[BB * GG];    // 32 KB: (cx, cy, log w, log h)
    __shared__ float redS[BB * 4];
    __shared__ float redC[BB * 4];

    const int t  = threadIdx.x;
    const int bx = blockIdx.x;

    // stage ALL images' gt boxes, pre-transformed (once per block)
#pragma unroll
    for (int i = 0; i < (BB * GG) / TPB; ++i) {
        const float4 g = gt[i * TPB + t];
        const float w = g.z - g.x;
        const float h = g.w - g.y;
        gts[i * TPB + t] = make_float4(g.x + 0.5f * w, g.y + 0.5f * h,
                                       __logf(w), __logf(h));
    }

    // per-anchor invariants (independent of LDS -> overlaps staging)
    const int a = bx * TPB + t;
    const float4 an = anc[a];
    const float ex_w  = an.z - an.x;
    const float ex_h  = an.w - an.y;
    const float ex_cx = an.x + 0.5f * ex_w;
    const float ex_cy = an.y + 0.5f * ex_h;
    const float inv_w = 1.0f / ex_w;
    const float inv_h = 1.0f / ex_h;
    const float lw    = __logf(ex_w);
    const float lh    = __logf(ex_h);

    // prefetch ALL matched indices (16 outstanding scalar loads)
    int mjv[BB];
#pragma unroll
    for (int b = 0; b < BB; ++b) mjv[b] = mi[b * AA + a];

    __syncthreads();   // gts ready

    const int wv   = t >> 6;
    const int lane = t & 63;

    // two half-batches: prefetch 8 float4 regs, then compute those 8
#pragma unroll
    for (int half = 0; half < 2; ++half) {
        float4 r[8];
#pragma unroll
        for (int j = 0; j < 8; ++j)
            r[j] = reg[(half * 8 + j) * AA + a];

#pragma unroll
        for (int j = 0; j < 8; ++j) {
            const int b  = half * 8 + j;
            const int mj = mjv[b];
            const float4 g = gts[b * GG + (mj < 0 ? 0 : mj)];

            const float dx = (g.x - ex_cx) * inv_w;
            const float dy = (g.y - ex_cy) * inv_h;
            const float dw = g.z - lw;
            const float dh = g.w - lh;

            const float l1 = fabsf(r[j].x - dx) + fabsf(r[j].y - dy) +
                             fabsf(r[j].z - dw) + fabsf(r[j].w - dh);
            float s = (mj >= 0) ? l1 : 0.0f;

            // sum via shuffle; count via ballot+popcount
            const unsigned long long bal = __ballot(mj >= 0);
#pragma unroll
            for (int o = 32; o > 0; o >>= 1) s += __shfl_down(s, o);

            if (lane == 0) {
                redS[b * 4 + wv] = s;
                redC[b * 4 + wv] = (float)__popcll(bal);
            }
        }
    }
    __syncthreads();

    if (t < BB) {
        const float s = redS[t * 4] + redS[t * 4 + 1] +
                        redS[t * 4 + 2] + redS[t * 4 + 3];
        const float c = redC[t * 4] + redC[t * 4 + 1] +
                        redC[t * 4 + 2] + redC[t * 4 + 3];
        ws_sum[t * NBLK + bx] = s;
        ws_cnt[t * NBLK + bx] = c;
    }
}

// single block: each wave reduces 4 images, thread 0 combines
__global__ __launch_bounds__(TPB) void reduce_final_kernel(
    const float* __restrict__ ws_sum,
    const float* __restrict__ ws_cnt,
    float* __restrict__ out)
{
    __shared__ float per_img[BB];
    const int t    = threadIdx.x;
    const int wv   = t >> 6;
    const int lane = t & 63;

#pragma unroll
    for (int k = 0; k < 4; ++k) {
        const int b = wv * 4 + k;
        float s = 0.0f, c = 0.0f;
#pragma unroll
        for (int i = 0; i < NBLK / 64; ++i) {
            s += ws_sum[b * NBLK + i * 64 + lane];
            c += ws_cnt[b * NBLK + i * 64 + lane];
        }
#pragma unroll
        for (int o = 32; o > 0; o >>= 1) {
            s += __shfl_down(s, o);
            c += __shfl_down(c, o);
        }
        if (lane == 0) per_img[b] = s / fmaxf(1.0f, c);
    }
    __syncthreads();

    if (t == 0) {
        float acc = 0.0f;
#pragma unroll
        for (int b = 0; b < BB; ++b) acc += per_img[b];
        out[0] = acc / (float)BB;
    }
}

extern "C" void kernel_launch(void* const* d_in, const int* in_sizes, int n_in,
                              void* d_out, int out_size, void* d_ws, size_t ws_size,
                              hipStream_t stream) {
    const float4* reg = (const float4*)d_in[0];   // bbox_regression [B,A,4]
    const float4* anc = (const float4*)d_in[1];   // anchors [A,4]
    const float4* gt  = (const float4*)d_in[2];   // gt_boxes [B,G,4]
    const int*    mi  = (const int*)d_in[3];      // matched_idxs [B,A]

    float* ws_sum = (float*)d_ws;
    float* ws_cnt = ws_sum + BB * NBLK;

    loss_main_kernel<<<NBLK, TPB, 0, stream>>>(reg, anc, gt, mi, ws_sum, ws_cnt);
    reduce_final_kernel<<<1, TPB, 0, stream>>>(ws_sum, ws_cnt, (float*)d_out);
}